// Round 1
// baseline (28307.513 us; speedup 1.0000x reference)
//
// KalmanNetNN persistent kernel, MI355X (gfx950).
// R9: attack exchange-wait (spin congestion) + l1 weight stream.
//   - gated polls: spin on word 0 only (8B/round vs 80B/round), then one
//     parallel verified settle round for the remaining words. All words of
//     a packet are stored by one coalesced wave-store, so word0 visibility
//     implies the rest are at worst in flight; per-word tags still verified.
//     Cuts MALL poll traffic ~8x; hot window widened to 32 rounds (cheap).
//   - w1e VGPR hoist: rows tid+h*512, h<4 (2048 rows) held in registers
//     across the whole sequence (LDS-bound at 1 block/CU -> VGPRs free).
//     Halves the 266KB/step/block L2 stream in small_chain's full-l1 loop.
//   - own-h in register (myh): B no longer reads HS -> post-B barrier dropped.
// Numerics bit-identical to R8.
// Predicted: step 16.2 -> ~13.7-14.6 us => ~7.0-7.5 ms.

#include <hip/hip_runtime.h>
#include <stdint.h>
#include <stddef.h>

typedef float v2f __attribute__((ext_vector_type(2)));

#define HID   2320
#define G3    6960
#define KIH   4160
#define KHH   2320
#define NBLK  232
#define NL2B  192              // blocks owning l2 rows (4 each = 768)
#define NTHR  512
#define UPB   10
#define TSEQ  512
#define KRES  1600
#define HQ    4                // w1e row-strides hoisted into VGPRs
#define INVWS (1.0f/128.0f)
#define SPINCAP (1u<<17)

// ---------------- workspace layout (bytes) ----------------
#define WS_WIH8 0L            // 6960*4160 fp8
#define WS_W1E  28953600L     // 4160*64 fp8 W1ext (52 w + b1 + pad)
#define WS_HBP  29219840L     // 2 x 232 x 128B h packets (10 tagged words)
#define WS_SLT  29279232L     // 2 x 232 x 64B slot packets (4 tagged words)
#define WS_END  29308928L

struct Offs {
  int l1s, hs, wih, whh, w2s, w3s, cs, as_, b3s, bih, bhh, b2s, gis, ghs,
      ts, inn, kn, dxs, xpri, xpo, b4, nrm, l2r, slp;
  int total;
};

__host__ __device__ inline Offs mkoffs(int res) {
  Offs o; int p = 0;
#define ALLOC(name, bytes) { p = (p + 15) & ~15; o.name = p; p += (bytes); }
  ALLOC(l1s, KIH*4) ALLOC(hs, HID*4)
  ALLOC(wih, res ? 30*KRES : 16) ALLOC(whh, res ? 30*KHH : 16)
  ALLOC(w2s, res ? 4*HID : 16)
  ALLOC(w3s, 16*48*4) ALLOC(cs, 240*4) ALLOC(as_, 64) ALLOC(b3s, 192*4)
  ALLOC(bih, 120) ALLOC(bhh, 120) ALLOC(b2s, 16)
  ALLOC(gis, 120) ALLOC(ghs, 120)
  ALLOC(ts, 64) ALLOC(inn, 192) ALLOC(kn, 256)
  ALLOC(dxs, 16) ALLOC(xpri, 16) ALLOC(xpo, 16) ALLOC(b4, 16) ALLOC(nrm, 16)
  ALLOC(l2r, 16) ALLOC(slp, 64)
#undef ALLOC
  o.total = (p + 63) & ~63;
  return o;
}

struct Params {
  const float *A, *C, *x0, *h0, *y, *W1, *b1, *Wih, *Whh, *bih, *bhh, *W2, *b2, *W3, *b3;
  const uint8_t *wih8, *w1e;
  uint64_t *hbp, *slt;
  float *out;
  int resident;
};

__device__ __forceinline__ uint8_t f2fp8(float v) {
  v = fminf(fmaxf(v * 128.f, -448.f), 448.f);
  int pk = __builtin_amdgcn_cvt_pk_fp8_f32(v, v, 0, false);
  return (uint8_t)(pk & 0xff);
}

// fire-and-forget tagged publish: one self-validating 8B word.
__device__ __forceinline__ void pub64(uint64_t* a, uint32_t tag, float v) {
  uint64_t w = ((uint64_t)tag << 32) | (uint64_t)__float_as_uint(v);
  __hip_atomic_store(a, w, __ATOMIC_RELAXED, __HIP_MEMORY_SCOPE_AGENT);
}

// gated poll: spin on word 0 (8B/round), then settle words 1..N-1 with
// parallel verified rounds (first round succeeds ~always since all N words
// come from one coalesced wave-store). Per-word tags still fully verified.
template<int N>
__device__ __forceinline__ void poll_pkt(const uint64_t* base, uint32_t want,
                                         float* out, bool& dead) {
  uint64_t v0;
  uint32_t spins = 0;
  for (;;) {
    v0 = __hip_atomic_load(base, __ATOMIC_RELAXED, __HIP_MEMORY_SCOPE_AGENT);
    if ((uint32_t)(v0 >> 32) == want || dead) break;
    ++spins;
    if (spins > 32) __builtin_amdgcn_s_sleep(2);
    if (spins > SPINCAP) dead = true;
  }
  out[0] = __uint_as_float((uint32_t)v0);
  if (N > 1) {
    uint64_t v[N];
    uint32_t s2 = 0;
    for (;;) {
      bool ok = true;
#pragma unroll
      for (int k = 1; k < N; ++k)
        v[k] = __hip_atomic_load(base + k, __ATOMIC_RELAXED, __HIP_MEMORY_SCOPE_AGENT);
#pragma unroll
      for (int k = 1; k < N; ++k) ok &= ((uint32_t)(v[k] >> 32) == want);
      if (ok || dead) break;
      ++s2;
      if (s2 > 8) __builtin_amdgcn_s_sleep(2);
      if (s2 > SPINCAP) dead = true;
    }
#pragma unroll
    for (int k = 1; k < N; ++k) out[k] = __uint_as_float((uint32_t)v[k]);
  }
}

// 16-wide fp8 dot fragment: acc += dot(fp8x16(w), [a0 a1 a2 a3])
__device__ __forceinline__ float fma16(uint4 w, float4 a0, float4 a1,
                                       float4 a2, float4 a3, float acc) {
  v2f l0 = __builtin_amdgcn_cvt_pk_f32_fp8((int)w.x, false);
  v2f h0 = __builtin_amdgcn_cvt_pk_f32_fp8((int)w.x, true);
  v2f l1 = __builtin_amdgcn_cvt_pk_f32_fp8((int)w.y, false);
  v2f h1 = __builtin_amdgcn_cvt_pk_f32_fp8((int)w.y, true);
  v2f l2 = __builtin_amdgcn_cvt_pk_f32_fp8((int)w.z, false);
  v2f h2 = __builtin_amdgcn_cvt_pk_f32_fp8((int)w.z, true);
  v2f l3 = __builtin_amdgcn_cvt_pk_f32_fp8((int)w.w, false);
  v2f h3 = __builtin_amdgcn_cvt_pk_f32_fp8((int)w.w, true);
  acc = fmaf(l0.x,a0.x,acc); acc = fmaf(l0.y,a0.y,acc);
  acc = fmaf(h0.x,a0.z,acc); acc = fmaf(h0.y,a0.w,acc);
  acc = fmaf(l1.x,a1.x,acc); acc = fmaf(l1.y,a1.y,acc);
  acc = fmaf(h1.x,a1.z,acc); acc = fmaf(h1.y,a1.w,acc);
  acc = fmaf(l2.x,a2.x,acc); acc = fmaf(l2.y,a2.y,acc);
  acc = fmaf(h2.x,a2.z,acc); acc = fmaf(h2.y,a2.w,acc);
  acc = fmaf(l3.x,a3.x,acc); acc = fmaf(l3.y,a3.y,acc);
  acc = fmaf(h3.x,a3.z,acc); acc = fmaf(h3.y,a3.w,acc);
  return acc;
}

// fp8 row-dot, LDS weights, <=4 rows/wave, lanes split K.
__device__ __forceinline__ void dot8_lds(
    const float* __restrict__ acts, const uint8_t* __restrict__ w, int stride,
    int K, const int* lrows, int nr, int lane, float acc[4])
{
  int kb = 0;
  for (; kb + 256 <= K; kb += 256) {
    const float4 a = ((const float4*)(acts + kb))[lane];
#pragma unroll
    for (int j = 0; j < 4; ++j) if (j < nr) {
      uint32_t wb = *(const uint32_t*)(w + (size_t)lrows[j]*stride + kb + (lane<<2));
      v2f lo = __builtin_amdgcn_cvt_pk_f32_fp8((int)wb, false);
      v2f hi = __builtin_amdgcn_cvt_pk_f32_fp8((int)wb, true);
      acc[j] = fmaf(lo.x, a.x, acc[j]); acc[j] = fmaf(lo.y, a.y, acc[j]);
      acc[j] = fmaf(hi.x, a.z, acc[j]); acc[j] = fmaf(hi.y, a.w, acc[j]);
    }
  }
  int rem = K - kb;
  if ((lane << 2) < rem) {
    const float4 a = ((const float4*)(acts + kb))[lane];
#pragma unroll
    for (int j = 0; j < 4; ++j) if (j < nr) {
      uint32_t wb = *(const uint32_t*)(w + (size_t)lrows[j]*stride + kb + (lane<<2));
      v2f lo = __builtin_amdgcn_cvt_pk_f32_fp8((int)wb, false);
      v2f hi = __builtin_amdgcn_cvt_pk_f32_fp8((int)wb, true);
      acc[j] = fmaf(lo.x, a.x, acc[j]); acc[j] = fmaf(lo.y, a.y, acc[j]);
      acc[j] = fmaf(hi.x, a.z, acc[j]); acc[j] = fmaf(hi.y, a.w, acc[j]);
    }
  }
}

// fp8 row-dot, global weights, cols [K0,K).
__device__ __forceinline__ void dot8_glb(
    const float* __restrict__ acts, const uint8_t* __restrict__ gw, int gstride,
    int K0, int K, const int* grows, int nr, int lane, float acc[4])
{
  int kb = K0;
  for (; kb + 512 <= K; kb += 512) {
    const float4 a0 = ((const float4*)(acts + kb))[lane*2];
    const float4 a1 = ((const float4*)(acts + kb))[lane*2 + 1];
#pragma unroll
    for (int j = 0; j < 4; ++j) if (j < nr) {
      uint2 wb = *(const uint2*)(gw + (size_t)grows[j]*gstride + kb + (lane<<3));
      v2f l0 = __builtin_amdgcn_cvt_pk_f32_fp8((int)wb.x, false);
      v2f h0 = __builtin_amdgcn_cvt_pk_f32_fp8((int)wb.x, true);
      v2f l1 = __builtin_amdgcn_cvt_pk_f32_fp8((int)wb.y, false);
      v2f h1 = __builtin_amdgcn_cvt_pk_f32_fp8((int)wb.y, true);
      acc[j] = fmaf(l0.x, a0.x, acc[j]); acc[j] = fmaf(l0.y, a0.y, acc[j]);
      acc[j] = fmaf(h0.x, a0.z, acc[j]); acc[j] = fmaf(h0.y, a0.w, acc[j]);
      acc[j] = fmaf(l1.x, a1.x, acc[j]); acc[j] = fmaf(l1.y, a1.y, acc[j]);
      acc[j] = fmaf(h1.x, a1.z, acc[j]); acc[j] = fmaf(h1.y, a1.w, acc[j]);
    }
  }
  for (int e = kb + lane; e < K; e += 64) {
    float a = acts[e];
#pragma unroll
    for (int j = 0; j < 4; ++j) if (j < nr) {
      v2f lo = __builtin_amdgcn_cvt_pk_f32_fp8(
          (int)(uint32_t)gw[(size_t)grows[j]*gstride + e], false);
      acc[j] = fmaf(lo.x, a, acc[j]);
    }
  }
}

// f32 row-dot, global weights (fallback ghh).
__device__ __forceinline__ void dotf_glb(
    const float* __restrict__ acts, const float* __restrict__ gw, int gstride,
    int K, const int* grows, int nr, int lane, float acc[4])
{
  for (int k = lane; k < K; k += 64) {
    float a = acts[k];
#pragma unroll
    for (int j = 0; j < 4; ++j) if (j < nr)
      acc[j] = fmaf(gw[(size_t)grows[j]*gstride + k], a, acc[j]);
  }
}

extern "C" __global__ void __launch_bounds__(NTHR, 2) knet_main(Params p)
{
  extern __shared__ char smem[];
  const Offs o = mkoffs(p.resident);
  float*   L1S  = (float*)(smem + o.l1s);
  float*   HS   = (float*)(smem + o.hs);
  uint8_t* WIHR = (uint8_t*)(smem + o.wih);
  uint8_t* WHHR = (uint8_t*)(smem + o.whh);
  uint8_t* W2S  = (uint8_t*)(smem + o.w2s);
  float*   W3S  = (float*)(smem + o.w3s);
  float*   CS   = (float*)(smem + o.cs);
  float*   AS   = (float*)(smem + o.as_);
  float*   B3S  = (float*)(smem + o.b3s);
  float*   BIH  = (float*)(smem + o.bih);
  float*   BHH  = (float*)(smem + o.bhh);
  float*   B2S  = (float*)(smem + o.b2s);
  float*   GIS  = (float*)(smem + o.gis);
  float*   GHS  = (float*)(smem + o.ghs);
  float*   TS   = (float*)(smem + o.ts);
  float*   INNS = (float*)(smem + o.inn);
  float*   KN   = (float*)(smem + o.kn);
  float*   DXS  = (float*)(smem + o.dxs);
  float*   XPRI = (float*)(smem + o.xpri);
  float*   XPO  = (float*)(smem + o.xpo);
  float*   B4   = (float*)(smem + o.b4);
  float*   NRM  = (float*)(smem + o.nrm);
  float*   L2R  = (float*)(smem + o.l2r);
  float*   SLP  = (float*)(smem + o.slp);

  const int tid  = (int)threadIdx.x;
  const int bid  = (int)blockIdx.x;
  const int lane = tid & 63;
  const int wv   = tid >> 6;
  const int rows2 = (bid < NL2B) ? 4 : 0;              // uniform l2 ownership
  const int r2s   = bid * 4;
  bool dead = false;

  int lrows[4] = {0,0,0,0}, grows[4] = {0,0,0,0};
  int nr = 0;
#pragma unroll
  for (int j = 0; j < 4; ++j) {
    int row = wv + 8*j;
    if (row < 30) { int u = row/3, g = row - 3*u;
      lrows[nr] = row; grows[nr] = g*HID + bid*UPB + u; ++nr; }
  }

  // ---------------- one-time staging ----------------
  for (int i = tid; i < rows2*192; i += NTHR) { int rl = i/192, rem = i - rl*192;
    W3S[i] = p.W3[(size_t)rem*768 + (r2s + rl)]; }
  for (int i = tid; i < 240; i += NTHR) CS[i] = p.C[i];
  if (tid < 16) AS[tid] = p.A[tid];
  for (int i = tid; i < 192; i += NTHR) B3S[i] = p.b3[i];
  if (tid < rows2) B2S[tid] = p.b2[r2s + tid];
  if (tid < 30) {
    int u = tid/3, g = tid - 3*u, ug = bid*UPB + u;
    BIH[tid] = p.bih[g*HID + ug];
    BHH[tid] = p.bhh[g*HID + ug];
  }
  for (int i = tid; i < HID; i += NTHR) HS[i] = p.h0[i];
  // own-unit hidden state held in a register (tid < UPB only).
  float myh = (tid < UPB) ? p.h0[(size_t)bid*UPB + tid] : 0.f;
  if (p.resident) {
    const int kd = KRES >> 2;                   // W_ih resident cols from fp8 ws
    uint32_t* W32 = (uint32_t*)WIHR;
    for (int i = tid; i < 30*kd; i += NTHR) {
      int row = i / kd, c = i - row*kd;
      int u = row/3, g = row - 3*u, gr = g*HID + bid*UPB + u;
      W32[i] = ((const uint32_t*)p.wih8)[(size_t)gr*(KIH/4) + c];
    }
    for (int i = tid; i < 30*KHH; i += NTHR) {  // W_hh rows f32->fp8
      int row = i / KHH, k = i - row*KHH;
      int u = row/3, g = row - 3*u, gr = g*HID + bid*UPB + u;
      WHHR[i] = f2fp8(p.Whh[(size_t)gr*KHH + k]);
    }
    for (int i = tid; i < rows2*HID; i += NTHR) { // W2 slice f32->fp8
      int rl = i / HID, k = i - rl*HID;
      W2S[i] = f2fp8(p.W2[(size_t)(r2s+rl)*HID + k]);
    }
  }
  // streamed W_ih cols [KRES,4160) hoisted into VGPRs (constant across steps)
  uint2 pf[4][5];
#pragma unroll
  for (int j = 0; j < 4; ++j)
#pragma unroll
    for (int i = 0; i < 5; ++i) pf[j][i] = make_uint2(0u, 0u);
#pragma unroll
  for (int j = 0; j < 4; ++j) if (j < nr)
#pragma unroll
    for (int i = 0; i < 5; ++i)
      pf[j][i] = *(const uint2*)(p.wih8 + (size_t)grows[j]*KIH + KRES + i*512 + (lane<<3));
  // w1e rows tid + h*NTHR, h<HQ hoisted into VGPRs (constant across steps);
  // LDS caps us at 1 block/CU so the extra 64 VGPRs are free occupancy-wise.
  uint4 w1h[HQ][4];
#pragma unroll
  for (int h = 0; h < HQ; ++h) {
    const uint4* wp = (const uint4*)(p.w1e + (size_t)(tid + h*NTHR)*64);
#pragma unroll
    for (int q = 0; q < 4; ++q) w1h[h][q] = wp[q];
  }
  __syncthreads();

  // small chain producing step-`ycol` inputs: INNS, KN, B4, TS, full l1.
  auto small_chain = [&](int ycol) {
    if (tid < 48) {
      float s = CS[tid*5 + 4];
#pragma unroll
      for (int k = 0; k < 4; ++k) s += CS[tid*5 + k] * XPRI[k];
      INNS[tid] = p.y[(size_t)tid*TSEQ + ycol] - s;
    }
    __syncthreads();
    if (wv == 0) {                               // parallel ||inn||
      float q = (lane < 48) ? INNS[lane]*INNS[lane] : 0.f;
#pragma unroll
      for (int m = 32; m >= 1; m >>= 1) q += __shfl_xor(q, m, 64);
      if (lane == 0) NRM[0] = fmaxf(sqrtf(q), 1e-12f);
    } else if (wv == 1) {                        // parallel ||dx||
      float q = (lane < 4) ? DXS[lane]*DXS[lane] : 0.f;
#pragma unroll
      for (int m = 32; m >= 1; m >>= 1) q += __shfl_xor(q, m, 64);
      if (lane == 0) NRM[1] = fmaxf(sqrtf(q), 1e-12f);
    }
    __syncthreads();
    if (tid < 48) KN[tid] = INNS[tid] / NRM[0];
    else if (tid < 52) KN[tid] = DXS[tid-48] / NRM[1];
    else if (tid == 52) KN[tid] = 1.0f;
    else if (tid < 64) KN[tid] = 0.0f;
    else if (tid < 68) {
      int i = tid - 64; float s = 0;
      for (int j = 0; j < 48; ++j) s += B3S[i*48 + j] * INNS[j];
      B4[i] = s;
    }
    if (tid >= 128 && tid < 128 + rows2*4) {
      int idx = tid - 128, rl = idx >> 2, i = idx & 3;
      float s = 0;
      for (int j = 0; j < 48; ++j) s += W3S[rl*192 + i*48 + j] * INNS[j];
      TS[i*4 + rl] = s;
    }
    __syncthreads();
    {                                            // redundant full l1
      float4 kn[16];
#pragma unroll
      for (int c = 0; c < 16; ++c) kn[c] = ((const float4*)KN)[c];
      // VGPR-resident rows
#pragma unroll
      for (int h = 0; h < HQ; ++h) {
        float acc = 0.f;
#pragma unroll
        for (int q = 0; q < 4; ++q)
          acc = fma16(w1h[h][q], kn[q*4+0], kn[q*4+1], kn[q*4+2], kn[q*4+3], acc);
        L1S[tid + h*NTHR] = fmaxf(acc * INVWS, 0.f);
      }
      // streamed rows
      for (int r = tid + HQ*NTHR; r < KIH; r += NTHR) {
        const uint4* wp = (const uint4*)(p.w1e + (size_t)r*64);
        float acc = 0.f;
#pragma unroll
        for (int q = 0; q < 4; ++q) {
          uint4 w = wp[q];
          acc = fma16(w, kn[q*4+0], kn[q*4+1], kn[q*4+2], kn[q*4+3], acc);
        }
        L1S[r] = fmaxf(acc * INVWS, 0.f);
      }
    }
    __syncthreads();
  };

  auto ghh = [&]() {                             // W_hh @ HS -> GHS
    float acc[4] = {0,0,0,0};
    if (p.resident) dot8_lds(HS, WHHR, KHH, KHH, lrows, nr, lane, acc);
    else            dotf_glb(HS, p.Whh, KHH, KHH, grows, nr, lane, acc);
#pragma unroll
    for (int m = 32; m >= 1; m >>= 1)
#pragma unroll
      for (int j = 0; j < 4; ++j) acc[j] += __shfl_xor(acc[j], m, 64);
    if (lane == 0)
#pragma unroll
      for (int j = 0; j < 4; ++j) if (j < nr) GHS[lrows[j]] = acc[j];
  };

  // ---------------- pre-loop ----------------
  if (tid < 4) { XPO[tid] = p.x0[tid]; DXS[tid] = 0.f; }
  __syncthreads();
  if (tid < 4) {
    float s = 0;
#pragma unroll
    for (int j = 0; j < 4; ++j) s += AS[tid*4 + j] * XPO[j];
    XPRI[tid] = s;
  }
  __syncthreads();
  small_chain(0);
  ghh();
  __syncthreads();

  // ---------------- main sequence ----------------
  for (int t = 0; t < TSEQ; ++t) {
    const int par = t & 1;
    const uint32_t want = (uint32_t)(t + 1);

    // ---- A: gate-dot gi = W_ih @ l1(t) ----
    {
      float acc[4] = {0,0,0,0};
      if (p.resident) dot8_lds(L1S, WIHR, KRES, KRES, lrows, nr, lane, acc);
      else            dot8_glb(L1S, p.wih8, KIH, 0, KRES, grows, nr, lane, acc);
#pragma unroll
      for (int i = 0; i < 5; ++i) {              // VGPR-held streamed cols
        const float4 a0 = ((const float4*)(L1S + KRES + i*512))[lane*2];
        const float4 a1 = ((const float4*)(L1S + KRES + i*512))[lane*2 + 1];
#pragma unroll
        for (int j = 0; j < 4; ++j) if (j < nr) {
          uint2 w = pf[j][i];
          v2f l0 = __builtin_amdgcn_cvt_pk_f32_fp8((int)w.x, false);
          v2f h0 = __builtin_amdgcn_cvt_pk_f32_fp8((int)w.x, true);
          v2f l1v = __builtin_amdgcn_cvt_pk_f32_fp8((int)w.y, false);
          v2f h1 = __builtin_amdgcn_cvt_pk_f32_fp8((int)w.y, true);
          acc[j] = fmaf(l0.x, a0.x, acc[j]); acc[j] = fmaf(l0.y, a0.y, acc[j]);
          acc[j] = fmaf(h0.x, a0.z, acc[j]); acc[j] = fmaf(h0.y, a0.w, acc[j]);
          acc[j] = fmaf(l1v.x, a1.x, acc[j]); acc[j] = fmaf(l1v.y, a1.y, acc[j]);
          acc[j] = fmaf(h1.x, a1.z, acc[j]); acc[j] = fmaf(h1.y, a1.w, acc[j]);
        }
      }
#pragma unroll
      for (int m = 32; m >= 1; m >>= 1)
#pragma unroll
        for (int j = 0; j < 4; ++j) acc[j] += __shfl_xor(acc[j], m, 64);
      if (lane == 0)
#pragma unroll
        for (int j = 0; j < 4; ++j) if (j < nr) GIS[lrows[j]] = acc[j];
    }
    __syncthreads();

    // ---- B: h(t) + fire-and-forget tagged publish (lanes 0..9) ----
    // B reads only GIS/GHS/BIH/BHH + register myh: no HS reads, so no
    // barrier needed before C overwrites HS.
    if (tid < UPB) {
      int r0 = tid*3;
      float gi0 = GIS[r0+0]*INVWS + BIH[r0+0], gh0 = GHS[r0+0]*INVWS + BHH[r0+0];
      float gi1 = GIS[r0+1]*INVWS + BIH[r0+1], gh1 = GHS[r0+1]*INVWS + BHH[r0+1];
      float gi2 = GIS[r0+2]*INVWS + BIH[r0+2], gh2 = GHS[r0+2]*INVWS + BHH[r0+2];
      float rg = 1.f/(1.f + expf(-(gi0+gh0)));
      float zg = 1.f/(1.f + expf(-(gi1+gh1)));
      float ng = tanhf(gi2 + rg*gh2);
      float hnew = (1.f - zg)*ng + zg*myh;
      myh = hnew;
      pub64(p.hbp + (((size_t)par*NBLK + bid) << 4) + tid, want, hnew);
    }

    // ---- C: h broadcast consume -> HS (waves 0-3) ----
    if (wv < 4) {
      int idx = (wv << 6) | lane;
      if (idx < NBLK) {
        float v[10];
        poll_pkt<10>(p.hbp + (((size_t)par*NBLK + idx) << 4), want, v, dead);
#pragma unroll
        for (int k = 0; k < 10; ++k) HS[idx*10 + k] = v[k];
      }
    }
    __syncthreads();

    // ---- D: l2 rows, one per wave on waves 4-7 (blocks < NL2B) ----
    if (rows2 && wv >= 4) {
      const int rl = wv - 4;
      float a2 = 0.f;
      if (p.resident) {
        int kb = 0;
        for (; kb + 256 <= HID; kb += 256) {
          const float4 a = ((const float4*)(HS + kb))[lane];
          uint32_t wb = *(const uint32_t*)(W2S + rl*HID + kb + (lane<<2));
          v2f lo = __builtin_amdgcn_cvt_pk_f32_fp8((int)wb, false);
          v2f hi = __builtin_amdgcn_cvt_pk_f32_fp8((int)wb, true);
          a2 = fmaf(lo.x, a.x, a2); a2 = fmaf(lo.y, a.y, a2);
          a2 = fmaf(hi.x, a.z, a2); a2 = fmaf(hi.y, a.w, a2);
        }
        if ((lane << 2) < HID - kb) {
          const float4 a = ((const float4*)(HS + kb))[lane];
          uint32_t wb = *(const uint32_t*)(W2S + rl*HID + kb + (lane<<2));
          v2f lo = __builtin_amdgcn_cvt_pk_f32_fp8((int)wb, false);
          v2f hi = __builtin_amdgcn_cvt_pk_f32_fp8((int)wb, true);
          a2 = fmaf(lo.x, a.x, a2); a2 = fmaf(lo.y, a.y, a2);
          a2 = fmaf(hi.x, a.z, a2); a2 = fmaf(hi.y, a.w, a2);
        }
        a2 *= INVWS;
      } else {
        for (int k = lane; k < HID; k += 64)
          a2 = fmaf(p.W2[(size_t)(r2s+rl)*HID + k], HS[k], a2);
      }
#pragma unroll
      for (int m = 32; m >= 1; m >>= 1) a2 += __shfl_xor(a2, m, 64);
      if (lane == 0) L2R[rl] = fmaxf(a2 + B2S[rl], 0.f);
    }
    __syncthreads();
    if (rows2 && tid < 4) {                      // publish 4 slot words
      float cp = L2R[0]*TS[tid*4+0] + L2R[1]*TS[tid*4+1]
               + L2R[2]*TS[tid*4+2] + L2R[3]*TS[tid*4+3];
      pub64(p.slt + (((size_t)par*NBLK + bid) << 3) + tid, want, cp);
    }

    // ---- E: ghh(t) for step t+1 (all waves; covers slot flight) ----
    ghh();

    // ---- F: slot reduce (waves 0-2: 192 packets) ----
    if (wv < 3) {
      int idx = (wv << 6) | lane;
      float v[4];
      poll_pkt<4>(p.slt + (((size_t)par*NBLK + idx) << 3), want, v, dead);
      float s0 = v[0], s1 = v[1], s2 = v[2], s3 = v[3];
#pragma unroll
      for (int m = 32; m >= 1; m >>= 1) {
        s0 += __shfl_xor(s0, m, 64); s1 += __shfl_xor(s1, m, 64);
        s2 += __shfl_xor(s2, m, 64); s3 += __shfl_xor(s3, m, 64);
      }
      if (lane == 0) {
        SLP[wv*4+0] = s0; SLP[wv*4+1] = s1; SLP[wv*4+2] = s2; SLP[wv*4+3] = s3;
      }
    }
    __syncthreads();

    // ---- G: posterior + next-step chain ----
    if (tid < 4) {
      float c = SLP[tid] + SLP[4 + tid] + SLP[8 + tid];
      float xp = XPRI[tid] + (c + B4[tid]) * 1e-4f;
      XPO[tid] = xp;
      if (bid == 0) p.out[(size_t)tid*TSEQ + t] = xp;
    }
    __syncthreads();
    if (t + 1 < TSEQ) {
      if (tid < 4) {
        float xo = XPO[tid];
        DXS[tid] = xo - XPRI[tid];
        float s = 0;
#pragma unroll
        for (int j = 0; j < 4; ++j) s += AS[tid*4 + j] * XPO[j];
        XPRI[tid] = s;
      }
      __syncthreads();
      small_chain(t + 1);                        // ends with syncthreads
    }
  }
}

// f32 -> fp8 e4m3 (x128), 4 elements per thread (W_ih full).
extern "C" __global__ void knet_cvt_fp8(const float* __restrict__ src,
                                        uint8_t* __restrict__ dst, long n4) {
  long stride = (long)gridDim.x * blockDim.x;
  for (long i = (long)blockIdx.x*blockDim.x + threadIdx.x; i < n4; i += stride) {
    float4 v = ((const float4*)src)[i];
    float a0 = fminf(fmaxf(v.x * 128.f, -448.f), 448.f);
    float a1 = fminf(fmaxf(v.y * 128.f, -448.f), 448.f);
    float a2 = fminf(fmaxf(v.z * 128.f, -448.f), 448.f);
    float a3 = fminf(fmaxf(v.w * 128.f, -448.f), 448.f);
    int pk = __builtin_amdgcn_cvt_pk_fp8_f32(a0, a1, 0, false);
    pk = __builtin_amdgcn_cvt_pk_fp8_f32(a2, a3, pk, true);
    ((uint32_t*)dst)[i] = (uint32_t)pk;
  }
}

// Build W1ext fp8: row r = [W1[r,0:52], b1[r], 0 x11] * 128, 64 B/row.
extern "C" __global__ void knet_build_w1e(const float* __restrict__ W1,
                                          const float* __restrict__ b1,
                                          uint8_t* __restrict__ dst) {
  int r = blockIdx.x * blockDim.x + threadIdx.x;
  if (r >= KIH) return;
  float v[64];
#pragma unroll 13
  for (int q = 0; q < 13; ++q) {
    float4 w = ((const float4*)(W1 + (size_t)r*52))[q];
    v[q*4+0] = w.x; v[q*4+1] = w.y; v[q*4+2] = w.z; v[q*4+3] = w.w;
  }
  v[52] = b1[r];
  for (int i = 53; i < 64; ++i) v[i] = 0.f;
  uint32_t out[16];
#pragma unroll 16
  for (int d = 0; d < 16; ++d) {
    float a0 = fminf(fmaxf(v[d*4+0] * 128.f, -448.f), 448.f);
    float a1 = fminf(fmaxf(v[d*4+1] * 128.f, -448.f), 448.f);
    float a2 = fminf(fmaxf(v[d*4+2] * 128.f, -448.f), 448.f);
    float a3 = fminf(fmaxf(v[d*4+3] * 128.f, -448.f), 448.f);
    int pk = __builtin_amdgcn_cvt_pk_fp8_f32(a0, a1, 0, false);
    pk = __builtin_amdgcn_cvt_pk_fp8_f32(a2, a3, pk, true);
    out[d] = (uint32_t)pk;
  }
  uint4* dp = (uint4*)(dst + (size_t)r*64);
#pragma unroll 4
  for (int q = 0; q < 4; ++q)
    dp[q] = make_uint4(out[q*4+0], out[q*4+1], out[q*4+2], out[q*4+3]);
}

extern "C" void kernel_launch(void* const* d_in, const int* in_sizes, int n_in,
                              void* d_out, int out_size, void* d_ws, size_t ws_size,
                              hipStream_t stream)
{
  if (ws_size < (size_t)WS_END) return;   // 29.3 MB (proven available)
  uint8_t* ws = (uint8_t*)d_ws;

  knet_cvt_fp8<<<2048, 256, 0, stream>>>((const float*)d_in[7], ws + WS_WIH8,
                                         (long)G3*KIH/4);
  knet_build_w1e<<<(KIH + 255)/256, 256, 0, stream>>>(
      (const float*)d_in[5], (const float*)d_in[6], ws + WS_W1E);
  // no memset needed: word tags are exact-match (t+1); 0xAA poison never matches

  int resident = 1;
  Offs o = mkoffs(resident);
  hipError_t e = hipFuncSetAttribute((const void*)knet_main,
                                     hipFuncAttributeMaxDynamicSharedMemorySize,
                                     o.total);
  if (e != hipSuccess) {
    resident = 0; o = mkoffs(resident);
    (void)hipFuncSetAttribute((const void*)knet_main,
                              hipFuncAttributeMaxDynamicSharedMemorySize, o.total);
  }

  Params p;
  p.A   = (const float*)d_in[0];  p.C   = (const float*)d_in[1];
  p.x0  = (const float*)d_in[2];  p.h0  = (const float*)d_in[3];
  p.y   = (const float*)d_in[4];
  p.W1  = (const float*)d_in[5];  p.b1  = (const float*)d_in[6];
  p.Wih = (const float*)d_in[7];  p.Whh = (const float*)d_in[8];
  p.bih = (const float*)d_in[9];  p.bhh = (const float*)d_in[10];
  p.W2  = (const float*)d_in[11]; p.b2  = (const float*)d_in[12];
  p.W3  = (const float*)d_in[13]; p.b3  = (const float*)d_in[14];
  p.wih8 = ws + WS_WIH8;
  p.w1e  = ws + WS_W1E;
  p.hbp  = (uint64_t*)(ws + WS_HBP);
  p.slt  = (uint64_t*)(ws + WS_SLT);
  p.out  = (float*)d_out;
  p.resident = resident;

  knet_main<<<NBLK, NTHR, (size_t)o.total, stream>>>(p);
}

// Round 2
// 8524.467 us; speedup vs baseline: 3.3207x; 3.3207x over previous
//
// KalmanNetNN persistent kernel, MI355X (gfx950).
// R10: revert R9's w1e VGPR hoist (it spilled to scratch: VGPR stayed 128,
//   hbm_bytes exploded 175MB -> 30GB, dur 8.3ms -> 28.3ms). Compiler will
//   not grow past its 128-VGPR target even though __launch_bounds__ permits
//   256 -- the hoist became a per-step HBM scratch stream.
// Kept from R9 (cheap, structurally sound, untestable in R9's run):
//   - gated polls: spin on word 0 only (8B/round vs 80B/round), then one
//     parallel verified settle round for words 1..N-1.
//   - own-h in register (myh): B reads no LDS that C overwrites -> post-B
//     barrier dropped (one fewer __syncthreads per step).
// Numerics bit-identical to R8.
// Predicted: FETCH back to ~144MB, VALUBusy ~30%, dur 7.2-8.2ms.

#include <hip/hip_runtime.h>
#include <stdint.h>
#include <stddef.h>

typedef float v2f __attribute__((ext_vector_type(2)));

#define HID   2320
#define G3    6960
#define KIH   4160
#define KHH   2320
#define NBLK  232
#define NL2B  192              // blocks owning l2 rows (4 each = 768)
#define NTHR  512
#define UPB   10
#define TSEQ  512
#define KRES  1600
#define INVWS (1.0f/128.0f)
#define SPINCAP (1u<<17)

// ---------------- workspace layout (bytes) ----------------
#define WS_WIH8 0L            // 6960*4160 fp8
#define WS_W1E  28953600L     // 4160*64 fp8 W1ext (52 w + b1 + pad)
#define WS_HBP  29219840L     // 2 x 232 x 128B h packets (10 tagged words)
#define WS_SLT  29279232L     // 2 x 232 x 64B slot packets (4 tagged words)
#define WS_END  29308928L

struct Offs {
  int l1s, hs, wih, whh, w2s, w3s, cs, as_, b3s, bih, bhh, b2s, gis, ghs,
      ts, inn, kn, dxs, xpri, xpo, b4, nrm, l2r, slp;
  int total;
};

__host__ __device__ inline Offs mkoffs(int res) {
  Offs o; int p = 0;
#define ALLOC(name, bytes) { p = (p + 15) & ~15; o.name = p; p += (bytes); }
  ALLOC(l1s, KIH*4) ALLOC(hs, HID*4)
  ALLOC(wih, res ? 30*KRES : 16) ALLOC(whh, res ? 30*KHH : 16)
  ALLOC(w2s, res ? 4*HID : 16)
  ALLOC(w3s, 16*48*4) ALLOC(cs, 240*4) ALLOC(as_, 64) ALLOC(b3s, 192*4)
  ALLOC(bih, 120) ALLOC(bhh, 120) ALLOC(b2s, 16)
  ALLOC(gis, 120) ALLOC(ghs, 120)
  ALLOC(ts, 64) ALLOC(inn, 192) ALLOC(kn, 256)
  ALLOC(dxs, 16) ALLOC(xpri, 16) ALLOC(xpo, 16) ALLOC(b4, 16) ALLOC(nrm, 16)
  ALLOC(l2r, 16) ALLOC(slp, 64)
#undef ALLOC
  o.total = (p + 63) & ~63;
  return o;
}

struct Params {
  const float *A, *C, *x0, *h0, *y, *W1, *b1, *Wih, *Whh, *bih, *bhh, *W2, *b2, *W3, *b3;
  const uint8_t *wih8, *w1e;
  uint64_t *hbp, *slt;
  float *out;
  int resident;
};

__device__ __forceinline__ uint8_t f2fp8(float v) {
  v = fminf(fmaxf(v * 128.f, -448.f), 448.f);
  int pk = __builtin_amdgcn_cvt_pk_fp8_f32(v, v, 0, false);
  return (uint8_t)(pk & 0xff);
}

// fire-and-forget tagged publish: one self-validating 8B word.
__device__ __forceinline__ void pub64(uint64_t* a, uint32_t tag, float v) {
  uint64_t w = ((uint64_t)tag << 32) | (uint64_t)__float_as_uint(v);
  __hip_atomic_store(a, w, __ATOMIC_RELAXED, __HIP_MEMORY_SCOPE_AGENT);
}

// gated poll: spin on word 0 (8B/round), then settle words 1..N-1 with
// parallel verified rounds (first round succeeds ~always since all N words
// come from one coalesced wave-store). Per-word tags still fully verified.
template<int N>
__device__ __forceinline__ void poll_pkt(const uint64_t* base, uint32_t want,
                                         float* out, bool& dead) {
  uint64_t v0;
  uint32_t spins = 0;
  for (;;) {
    v0 = __hip_atomic_load(base, __ATOMIC_RELAXED, __HIP_MEMORY_SCOPE_AGENT);
    if ((uint32_t)(v0 >> 32) == want || dead) break;
    ++spins;
    if (spins > 32) __builtin_amdgcn_s_sleep(2);
    if (spins > SPINCAP) dead = true;
  }
  out[0] = __uint_as_float((uint32_t)v0);
  if (N > 1) {
    uint64_t v[N];
    uint32_t s2 = 0;
    for (;;) {
      bool ok = true;
#pragma unroll
      for (int k = 1; k < N; ++k)
        v[k] = __hip_atomic_load(base + k, __ATOMIC_RELAXED, __HIP_MEMORY_SCOPE_AGENT);
#pragma unroll
      for (int k = 1; k < N; ++k) ok &= ((uint32_t)(v[k] >> 32) == want);
      if (ok || dead) break;
      ++s2;
      if (s2 > 8) __builtin_amdgcn_s_sleep(2);
      if (s2 > SPINCAP) dead = true;
    }
#pragma unroll
    for (int k = 1; k < N; ++k) out[k] = __uint_as_float((uint32_t)v[k]);
  }
}

// 16-wide fp8 dot fragment: acc += dot(fp8x16(w), [a0 a1 a2 a3])
__device__ __forceinline__ float fma16(uint4 w, float4 a0, float4 a1,
                                       float4 a2, float4 a3, float acc) {
  v2f l0 = __builtin_amdgcn_cvt_pk_f32_fp8((int)w.x, false);
  v2f h0 = __builtin_amdgcn_cvt_pk_f32_fp8((int)w.x, true);
  v2f l1 = __builtin_amdgcn_cvt_pk_f32_fp8((int)w.y, false);
  v2f h1 = __builtin_amdgcn_cvt_pk_f32_fp8((int)w.y, true);
  v2f l2 = __builtin_amdgcn_cvt_pk_f32_fp8((int)w.z, false);
  v2f h2 = __builtin_amdgcn_cvt_pk_f32_fp8((int)w.z, true);
  v2f l3 = __builtin_amdgcn_cvt_pk_f32_fp8((int)w.w, false);
  v2f h3 = __builtin_amdgcn_cvt_pk_f32_fp8((int)w.w, true);
  acc = fmaf(l0.x,a0.x,acc); acc = fmaf(l0.y,a0.y,acc);
  acc = fmaf(h0.x,a0.z,acc); acc = fmaf(h0.y,a0.w,acc);
  acc = fmaf(l1.x,a1.x,acc); acc = fmaf(l1.y,a1.y,acc);
  acc = fmaf(h1.x,a1.z,acc); acc = fmaf(h1.y,a1.w,acc);
  acc = fmaf(l2.x,a2.x,acc); acc = fmaf(l2.y,a2.y,acc);
  acc = fmaf(h2.x,a2.z,acc); acc = fmaf(h2.y,a2.w,acc);
  acc = fmaf(l3.x,a3.x,acc); acc = fmaf(l3.y,a3.y,acc);
  acc = fmaf(h3.x,a3.z,acc); acc = fmaf(h3.y,a3.w,acc);
  return acc;
}

// fp8 row-dot, LDS weights, <=4 rows/wave, lanes split K.
__device__ __forceinline__ void dot8_lds(
    const float* __restrict__ acts, const uint8_t* __restrict__ w, int stride,
    int K, const int* lrows, int nr, int lane, float acc[4])
{
  int kb = 0;
  for (; kb + 256 <= K; kb += 256) {
    const float4 a = ((const float4*)(acts + kb))[lane];
#pragma unroll
    for (int j = 0; j < 4; ++j) if (j < nr) {
      uint32_t wb = *(const uint32_t*)(w + (size_t)lrows[j]*stride + kb + (lane<<2));
      v2f lo = __builtin_amdgcn_cvt_pk_f32_fp8((int)wb, false);
      v2f hi = __builtin_amdgcn_cvt_pk_f32_fp8((int)wb, true);
      acc[j] = fmaf(lo.x, a.x, acc[j]); acc[j] = fmaf(lo.y, a.y, acc[j]);
      acc[j] = fmaf(hi.x, a.z, acc[j]); acc[j] = fmaf(hi.y, a.w, acc[j]);
    }
  }
  int rem = K - kb;
  if ((lane << 2) < rem) {
    const float4 a = ((const float4*)(acts + kb))[lane];
#pragma unroll
    for (int j = 0; j < 4; ++j) if (j < nr) {
      uint32_t wb = *(const uint32_t*)(w + (size_t)lrows[j]*stride + kb + (lane<<2));
      v2f lo = __builtin_amdgcn_cvt_pk_f32_fp8((int)wb, false);
      v2f hi = __builtin_amdgcn_cvt_pk_f32_fp8((int)wb, true);
      acc[j] = fmaf(lo.x, a.x, acc[j]); acc[j] = fmaf(lo.y, a.y, acc[j]);
      acc[j] = fmaf(hi.x, a.z, acc[j]); acc[j] = fmaf(hi.y, a.w, acc[j]);
    }
  }
}

// fp8 row-dot, global weights, cols [K0,K).
__device__ __forceinline__ void dot8_glb(
    const float* __restrict__ acts, const uint8_t* __restrict__ gw, int gstride,
    int K0, int K, const int* grows, int nr, int lane, float acc[4])
{
  int kb = K0;
  for (; kb + 512 <= K; kb += 512) {
    const float4 a0 = ((const float4*)(acts + kb))[lane*2];
    const float4 a1 = ((const float4*)(acts + kb))[lane*2 + 1];
#pragma unroll
    for (int j = 0; j < 4; ++j) if (j < nr) {
      uint2 wb = *(const uint2*)(gw + (size_t)grows[j]*gstride + kb + (lane<<3));
      v2f l0 = __builtin_amdgcn_cvt_pk_f32_fp8((int)wb.x, false);
      v2f h0 = __builtin_amdgcn_cvt_pk_f32_fp8((int)wb.x, true);
      v2f l1 = __builtin_amdgcn_cvt_pk_f32_fp8((int)wb.y, false);
      v2f h1 = __builtin_amdgcn_cvt_pk_f32_fp8((int)wb.y, true);
      acc[j] = fmaf(l0.x, a0.x, acc[j]); acc[j] = fmaf(l0.y, a0.y, acc[j]);
      acc[j] = fmaf(h0.x, a0.z, acc[j]); acc[j] = fmaf(h0.y, a0.w, acc[j]);
      acc[j] = fmaf(l1.x, a1.x, acc[j]); acc[j] = fmaf(l1.y, a1.y, acc[j]);
      acc[j] = fmaf(h1.x, a1.z, acc[j]); acc[j] = fmaf(h1.y, a1.w, acc[j]);
    }
  }
  for (int e = kb + lane; e < K; e += 64) {
    float a = acts[e];
#pragma unroll
    for (int j = 0; j < 4; ++j) if (j < nr) {
      v2f lo = __builtin_amdgcn_cvt_pk_f32_fp8(
          (int)(uint32_t)gw[(size_t)grows[j]*gstride + e], false);
      acc[j] = fmaf(lo.x, a, acc[j]);
    }
  }
}

// f32 row-dot, global weights (fallback ghh).
__device__ __forceinline__ void dotf_glb(
    const float* __restrict__ acts, const float* __restrict__ gw, int gstride,
    int K, const int* grows, int nr, int lane, float acc[4])
{
  for (int k = lane; k < K; k += 64) {
    float a = acts[k];
#pragma unroll
    for (int j = 0; j < 4; ++j) if (j < nr)
      acc[j] = fmaf(gw[(size_t)grows[j]*gstride + k], a, acc[j]);
  }
}

extern "C" __global__ void __launch_bounds__(NTHR, 2) knet_main(Params p)
{
  extern __shared__ char smem[];
  const Offs o = mkoffs(p.resident);
  float*   L1S  = (float*)(smem + o.l1s);
  float*   HS   = (float*)(smem + o.hs);
  uint8_t* WIHR = (uint8_t*)(smem + o.wih);
  uint8_t* WHHR = (uint8_t*)(smem + o.whh);
  uint8_t* W2S  = (uint8_t*)(smem + o.w2s);
  float*   W3S  = (float*)(smem + o.w3s);
  float*   CS   = (float*)(smem + o.cs);
  float*   AS   = (float*)(smem + o.as_);
  float*   B3S  = (float*)(smem + o.b3s);
  float*   BIH  = (float*)(smem + o.bih);
  float*   BHH  = (float*)(smem + o.bhh);
  float*   B2S  = (float*)(smem + o.b2s);
  float*   GIS  = (float*)(smem + o.gis);
  float*   GHS  = (float*)(smem + o.ghs);
  float*   TS   = (float*)(smem + o.ts);
  float*   INNS = (float*)(smem + o.inn);
  float*   KN   = (float*)(smem + o.kn);
  float*   DXS  = (float*)(smem + o.dxs);
  float*   XPRI = (float*)(smem + o.xpri);
  float*   XPO  = (float*)(smem + o.xpo);
  float*   B4   = (float*)(smem + o.b4);
  float*   NRM  = (float*)(smem + o.nrm);
  float*   L2R  = (float*)(smem + o.l2r);
  float*   SLP  = (float*)(smem + o.slp);

  const int tid  = (int)threadIdx.x;
  const int bid  = (int)blockIdx.x;
  const int lane = tid & 63;
  const int wv   = tid >> 6;
  const int rows2 = (bid < NL2B) ? 4 : 0;              // uniform l2 ownership
  const int r2s   = bid * 4;
  bool dead = false;

  int lrows[4] = {0,0,0,0}, grows[4] = {0,0,0,0};
  int nr = 0;
#pragma unroll
  for (int j = 0; j < 4; ++j) {
    int row = wv + 8*j;
    if (row < 30) { int u = row/3, g = row - 3*u;
      lrows[nr] = row; grows[nr] = g*HID + bid*UPB + u; ++nr; }
  }

  // ---------------- one-time staging ----------------
  for (int i = tid; i < rows2*192; i += NTHR) { int rl = i/192, rem = i - rl*192;
    W3S[i] = p.W3[(size_t)rem*768 + (r2s + rl)]; }
  for (int i = tid; i < 240; i += NTHR) CS[i] = p.C[i];
  if (tid < 16) AS[tid] = p.A[tid];
  for (int i = tid; i < 192; i += NTHR) B3S[i] = p.b3[i];
  if (tid < rows2) B2S[tid] = p.b2[r2s + tid];
  if (tid < 30) {
    int u = tid/3, g = tid - 3*u, ug = bid*UPB + u;
    BIH[tid] = p.bih[g*HID + ug];
    BHH[tid] = p.bhh[g*HID + ug];
  }
  for (int i = tid; i < HID; i += NTHR) HS[i] = p.h0[i];
  // own-unit hidden state held in a register (tid < UPB only).
  float myh = (tid < UPB) ? p.h0[(size_t)bid*UPB + tid] : 0.f;
  if (p.resident) {
    const int kd = KRES >> 2;                   // W_ih resident cols from fp8 ws
    uint32_t* W32 = (uint32_t*)WIHR;
    for (int i = tid; i < 30*kd; i += NTHR) {
      int row = i / kd, c = i - row*kd;
      int u = row/3, g = row - 3*u, gr = g*HID + bid*UPB + u;
      W32[i] = ((const uint32_t*)p.wih8)[(size_t)gr*(KIH/4) + c];
    }
    for (int i = tid; i < 30*KHH; i += NTHR) {  // W_hh rows f32->fp8
      int row = i / KHH, k = i - row*KHH;
      int u = row/3, g = row - 3*u, gr = g*HID + bid*UPB + u;
      WHHR[i] = f2fp8(p.Whh[(size_t)gr*KHH + k]);
    }
    for (int i = tid; i < rows2*HID; i += NTHR) { // W2 slice f32->fp8
      int rl = i / HID, k = i - rl*HID;
      W2S[i] = f2fp8(p.W2[(size_t)(r2s+rl)*HID + k]);
    }
  }
  // streamed W_ih cols [KRES,4160) hoisted into VGPRs (constant across steps)
  uint2 pf[4][5];
#pragma unroll
  for (int j = 0; j < 4; ++j)
#pragma unroll
    for (int i = 0; i < 5; ++i) pf[j][i] = make_uint2(0u, 0u);
#pragma unroll
  for (int j = 0; j < 4; ++j) if (j < nr)
#pragma unroll
    for (int i = 0; i < 5; ++i)
      pf[j][i] = *(const uint2*)(p.wih8 + (size_t)grows[j]*KIH + KRES + i*512 + (lane<<3));
  __syncthreads();

  // small chain producing step-`ycol` inputs: INNS, KN, B4, TS, full l1.
  auto small_chain = [&](int ycol) {
    if (tid < 48) {
      float s = CS[tid*5 + 4];
#pragma unroll
      for (int k = 0; k < 4; ++k) s += CS[tid*5 + k] * XPRI[k];
      INNS[tid] = p.y[(size_t)tid*TSEQ + ycol] - s;
    }
    __syncthreads();
    if (wv == 0) {                               // parallel ||inn||
      float q = (lane < 48) ? INNS[lane]*INNS[lane] : 0.f;
#pragma unroll
      for (int m = 32; m >= 1; m >>= 1) q += __shfl_xor(q, m, 64);
      if (lane == 0) NRM[0] = fmaxf(sqrtf(q), 1e-12f);
    } else if (wv == 1) {                        // parallel ||dx||
      float q = (lane < 4) ? DXS[lane]*DXS[lane] : 0.f;
#pragma unroll
      for (int m = 32; m >= 1; m >>= 1) q += __shfl_xor(q, m, 64);
      if (lane == 0) NRM[1] = fmaxf(sqrtf(q), 1e-12f);
    }
    __syncthreads();
    if (tid < 48) KN[tid] = INNS[tid] / NRM[0];
    else if (tid < 52) KN[tid] = DXS[tid-48] / NRM[1];
    else if (tid == 52) KN[tid] = 1.0f;
    else if (tid < 64) KN[tid] = 0.0f;
    else if (tid < 68) {
      int i = tid - 64; float s = 0;
      for (int j = 0; j < 48; ++j) s += B3S[i*48 + j] * INNS[j];
      B4[i] = s;
    }
    if (tid >= 128 && tid < 128 + rows2*4) {
      int idx = tid - 128, rl = idx >> 2, i = idx & 3;
      float s = 0;
      for (int j = 0; j < 48; ++j) s += W3S[rl*192 + i*48 + j] * INNS[j];
      TS[i*4 + rl] = s;
    }
    __syncthreads();
    {                                            // redundant full l1
      float4 kn[16];
#pragma unroll
      for (int c = 0; c < 16; ++c) kn[c] = ((const float4*)KN)[c];
      for (int r = tid; r < KIH; r += NTHR) {
        const uint4* wp = (const uint4*)(p.w1e + (size_t)r*64);
        float acc = 0.f;
#pragma unroll
        for (int q = 0; q < 4; ++q) {
          uint4 w = wp[q];
          acc = fma16(w, kn[q*4+0], kn[q*4+1], kn[q*4+2], kn[q*4+3], acc);
        }
        L1S[r] = fmaxf(acc * INVWS, 0.f);
      }
    }
    __syncthreads();
  };

  auto ghh = [&]() {                             // W_hh @ HS -> GHS
    float acc[4] = {0,0,0,0};
    if (p.resident) dot8_lds(HS, WHHR, KHH, KHH, lrows, nr, lane, acc);
    else            dotf_glb(HS, p.Whh, KHH, KHH, grows, nr, lane, acc);
#pragma unroll
    for (int m = 32; m >= 1; m >>= 1)
#pragma unroll
      for (int j = 0; j < 4; ++j) acc[j] += __shfl_xor(acc[j], m, 64);
    if (lane == 0)
#pragma unroll
      for (int j = 0; j < 4; ++j) if (j < nr) GHS[lrows[j]] = acc[j];
  };

  // ---------------- pre-loop ----------------
  if (tid < 4) { XPO[tid] = p.x0[tid]; DXS[tid] = 0.f; }
  __syncthreads();
  if (tid < 4) {
    float s = 0;
#pragma unroll
    for (int j = 0; j < 4; ++j) s += AS[tid*4 + j] * XPO[j];
    XPRI[tid] = s;
  }
  __syncthreads();
  small_chain(0);
  ghh();
  __syncthreads();

  // ---------------- main sequence ----------------
  for (int t = 0; t < TSEQ; ++t) {
    const int par = t & 1;
    const uint32_t want = (uint32_t)(t + 1);

    // ---- A: gate-dot gi = W_ih @ l1(t) ----
    {
      float acc[4] = {0,0,0,0};
      if (p.resident) dot8_lds(L1S, WIHR, KRES, KRES, lrows, nr, lane, acc);
      else            dot8_glb(L1S, p.wih8, KIH, 0, KRES, grows, nr, lane, acc);
#pragma unroll
      for (int i = 0; i < 5; ++i) {              // VGPR-held streamed cols
        const float4 a0 = ((const float4*)(L1S + KRES + i*512))[lane*2];
        const float4 a1 = ((const float4*)(L1S + KRES + i*512))[lane*2 + 1];
#pragma unroll
        for (int j = 0; j < 4; ++j) if (j < nr) {
          uint2 w = pf[j][i];
          v2f l0 = __builtin_amdgcn_cvt_pk_f32_fp8((int)w.x, false);
          v2f h0 = __builtin_amdgcn_cvt_pk_f32_fp8((int)w.x, true);
          v2f l1v = __builtin_amdgcn_cvt_pk_f32_fp8((int)w.y, false);
          v2f h1 = __builtin_amdgcn_cvt_pk_f32_fp8((int)w.y, true);
          acc[j] = fmaf(l0.x, a0.x, acc[j]); acc[j] = fmaf(l0.y, a0.y, acc[j]);
          acc[j] = fmaf(h0.x, a0.z, acc[j]); acc[j] = fmaf(h0.y, a0.w, acc[j]);
          acc[j] = fmaf(l1v.x, a1.x, acc[j]); acc[j] = fmaf(l1v.y, a1.y, acc[j]);
          acc[j] = fmaf(h1.x, a1.z, acc[j]); acc[j] = fmaf(h1.y, a1.w, acc[j]);
        }
      }
#pragma unroll
      for (int m = 32; m >= 1; m >>= 1)
#pragma unroll
        for (int j = 0; j < 4; ++j) acc[j] += __shfl_xor(acc[j], m, 64);
      if (lane == 0)
#pragma unroll
        for (int j = 0; j < 4; ++j) if (j < nr) GIS[lrows[j]] = acc[j];
    }
    __syncthreads();

    // ---- B: h(t) + fire-and-forget tagged publish (lanes 0..9) ----
    // B reads only GIS/GHS/BIH/BHH + register myh: no HS reads, so no
    // barrier needed before C overwrites HS.
    if (tid < UPB) {
      int r0 = tid*3;
      float gi0 = GIS[r0+0]*INVWS + BIH[r0+0], gh0 = GHS[r0+0]*INVWS + BHH[r0+0];
      float gi1 = GIS[r0+1]*INVWS + BIH[r0+1], gh1 = GHS[r0+1]*INVWS + BHH[r0+1];
      float gi2 = GIS[r0+2]*INVWS + BIH[r0+2], gh2 = GHS[r0+2]*INVWS + BHH[r0+2];
      float rg = 1.f/(1.f + expf(-(gi0+gh0)));
      float zg = 1.f/(1.f + expf(-(gi1+gh1)));
      float ng = tanhf(gi2 + rg*gh2);
      float hnew = (1.f - zg)*ng + zg*myh;
      myh = hnew;
      pub64(p.hbp + (((size_t)par*NBLK + bid) << 4) + tid, want, hnew);
    }

    // ---- C: h broadcast consume -> HS (waves 0-3) ----
    if (wv < 4) {
      int idx = (wv << 6) | lane;
      if (idx < NBLK) {
        float v[10];
        poll_pkt<10>(p.hbp + (((size_t)par*NBLK + idx) << 4), want, v, dead);
#pragma unroll
        for (int k = 0; k < 10; ++k) HS[idx*10 + k] = v[k];
      }
    }
    __syncthreads();

    // ---- D: l2 rows, one per wave on waves 4-7 (blocks < NL2B) ----
    if (rows2 && wv >= 4) {
      const int rl = wv - 4;
      float a2 = 0.f;
      if (p.resident) {
        int kb = 0;
        for (; kb + 256 <= HID; kb += 256) {
          const float4 a = ((const float4*)(HS + kb))[lane];
          uint32_t wb = *(const uint32_t*)(W2S + rl*HID + kb + (lane<<2));
          v2f lo = __builtin_amdgcn_cvt_pk_f32_fp8((int)wb, false);
          v2f hi = __builtin_amdgcn_cvt_pk_f32_fp8((int)wb, true);
          a2 = fmaf(lo.x, a.x, a2); a2 = fmaf(lo.y, a.y, a2);
          a2 = fmaf(hi.x, a.z, a2); a2 = fmaf(hi.y, a.w, a2);
        }
        if ((lane << 2) < HID - kb) {
          const float4 a = ((const float4*)(HS + kb))[lane];
          uint32_t wb = *(const uint32_t*)(W2S + rl*HID + kb + (lane<<2));
          v2f lo = __builtin_amdgcn_cvt_pk_f32_fp8((int)wb, false);
          v2f hi = __builtin_amdgcn_cvt_pk_f32_fp8((int)wb, true);
          a2 = fmaf(lo.x, a.x, a2); a2 = fmaf(lo.y, a.y, a2);
          a2 = fmaf(hi.x, a.z, a2); a2 = fmaf(hi.y, a.w, a2);
        }
        a2 *= INVWS;
      } else {
        for (int k = lane; k < HID; k += 64)
          a2 = fmaf(p.W2[(size_t)(r2s+rl)*HID + k], HS[k], a2);
      }
#pragma unroll
      for (int m = 32; m >= 1; m >>= 1) a2 += __shfl_xor(a2, m, 64);
      if (lane == 0) L2R[rl] = fmaxf(a2 + B2S[rl], 0.f);
    }
    __syncthreads();
    if (rows2 && tid < 4) {                      // publish 4 slot words
      float cp = L2R[0]*TS[tid*4+0] + L2R[1]*TS[tid*4+1]
               + L2R[2]*TS[tid*4+2] + L2R[3]*TS[tid*4+3];
      pub64(p.slt + (((size_t)par*NBLK + bid) << 3) + tid, want, cp);
    }

    // ---- E: ghh(t) for step t+1 (all waves; covers slot flight) ----
    ghh();

    // ---- F: slot reduce (waves 0-2: 192 packets) ----
    if (wv < 3) {
      int idx = (wv << 6) | lane;
      float v[4];
      poll_pkt<4>(p.slt + (((size_t)par*NBLK + idx) << 3), want, v, dead);
      float s0 = v[0], s1 = v[1], s2 = v[2], s3 = v[3];
#pragma unroll
      for (int m = 32; m >= 1; m >>= 1) {
        s0 += __shfl_xor(s0, m, 64); s1 += __shfl_xor(s1, m, 64);
        s2 += __shfl_xor(s2, m, 64); s3 += __shfl_xor(s3, m, 64);
      }
      if (lane == 0) {
        SLP[wv*4+0] = s0; SLP[wv*4+1] = s1; SLP[wv*4+2] = s2; SLP[wv*4+3] = s3;
      }
    }
    __syncthreads();

    // ---- G: posterior + next-step chain ----
    if (tid < 4) {
      float c = SLP[tid] + SLP[4 + tid] + SLP[8 + tid];
      float xp = XPRI[tid] + (c + B4[tid]) * 1e-4f;
      XPO[tid] = xp;
      if (bid == 0) p.out[(size_t)tid*TSEQ + t] = xp;
    }
    __syncthreads();
    if (t + 1 < TSEQ) {
      if (tid < 4) {
        float xo = XPO[tid];
        DXS[tid] = xo - XPRI[tid];
        float s = 0;
#pragma unroll
        for (int j = 0; j < 4; ++j) s += AS[tid*4 + j] * XPO[j];
        XPRI[tid] = s;
      }
      __syncthreads();
      small_chain(t + 1);                        // ends with syncthreads
    }
  }
}

// f32 -> fp8 e4m3 (x128), 4 elements per thread (W_ih full).
extern "C" __global__ void knet_cvt_fp8(const float* __restrict__ src,
                                        uint8_t* __restrict__ dst, long n4) {
  long stride = (long)gridDim.x * blockDim.x;
  for (long i = (long)blockIdx.x*blockDim.x + threadIdx.x; i < n4; i += stride) {
    float4 v = ((const float4*)src)[i];
    float a0 = fminf(fmaxf(v.x * 128.f, -448.f), 448.f);
    float a1 = fminf(fmaxf(v.y * 128.f, -448.f), 448.f);
    float a2 = fminf(fmaxf(v.z * 128.f, -448.f), 448.f);
    float a3 = fminf(fmaxf(v.w * 128.f, -448.f), 448.f);
    int pk = __builtin_amdgcn_cvt_pk_fp8_f32(a0, a1, 0, false);
    pk = __builtin_amdgcn_cvt_pk_fp8_f32(a2, a3, pk, true);
    ((uint32_t*)dst)[i] = (uint32_t)pk;
  }
}

// Build W1ext fp8: row r = [W1[r,0:52], b1[r], 0 x11] * 128, 64 B/row.
extern "C" __global__ void knet_build_w1e(const float* __restrict__ W1,
                                          const float* __restrict__ b1,
                                          uint8_t* __restrict__ dst) {
  int r = blockIdx.x * blockDim.x + threadIdx.x;
  if (r >= KIH) return;
  float v[64];
#pragma unroll 13
  for (int q = 0; q < 13; ++q) {
    float4 w = ((const float4*)(W1 + (size_t)r*52))[q];
    v[q*4+0] = w.x; v[q*4+1] = w.y; v[q*4+2] = w.z; v[q*4+3] = w.w;
  }
  v[52] = b1[r];
  for (int i = 53; i < 64; ++i) v[i] = 0.f;
  uint32_t out[16];
#pragma unroll 16
  for (int d = 0; d < 16; ++d) {
    float a0 = fminf(fmaxf(v[d*4+0] * 128.f, -448.f), 448.f);
    float a1 = fminf(fmaxf(v[d*4+1] * 128.f, -448.f), 448.f);
    float a2 = fminf(fmaxf(v[d*4+2] * 128.f, -448.f), 448.f);
    float a3 = fminf(fmaxf(v[d*4+3] * 128.f, -448.f), 448.f);
    int pk = __builtin_amdgcn_cvt_pk_fp8_f32(a0, a1, 0, false);
    pk = __builtin_amdgcn_cvt_pk_fp8_f32(a2, a3, pk, true);
    out[d] = (uint32_t)pk;
  }
  uint4* dp = (uint4*)(dst + (size_t)r*64);
#pragma unroll 4
  for (int q = 0; q < 4; ++q)
    dp[q] = make_uint4(out[q*4+0], out[q*4+1], out[q*4+2], out[q*4+3]);
}

extern "C" void kernel_launch(void* const* d_in, const int* in_sizes, int n_in,
                              void* d_out, int out_size, void* d_ws, size_t ws_size,
                              hipStream_t stream)
{
  if (ws_size < (size_t)WS_END) return;   // 29.3 MB (proven available)
  uint8_t* ws = (uint8_t*)d_ws;

  knet_cvt_fp8<<<2048, 256, 0, stream>>>((const float*)d_in[7], ws + WS_WIH8,
                                         (long)G3*KIH/4);
  knet_build_w1e<<<(KIH + 255)/256, 256, 0, stream>>>(
      (const float*)d_in[5], (const float*)d_in[6], ws + WS_W1E);
  // no memset needed: word tags are exact-match (t+1); 0xAA poison never matches

  int resident = 1;
  Offs o = mkoffs(resident);
  hipError_t e = hipFuncSetAttribute((const void*)knet_main,
                                     hipFuncAttributeMaxDynamicSharedMemorySize,
                                     o.total);
  if (e != hipSuccess) {
    resident = 0; o = mkoffs(resident);
    (void)hipFuncSetAttribute((const void*)knet_main,
                              hipFuncAttributeMaxDynamicSharedMemorySize, o.total);
  }

  Params p;
  p.A   = (const float*)d_in[0];  p.C   = (const float*)d_in[1];
  p.x0  = (const float*)d_in[2];  p.h0  = (const float*)d_in[3];
  p.y   = (const float*)d_in[4];
  p.W1  = (const float*)d_in[5];  p.b1  = (const float*)d_in[6];
  p.Wih = (const float*)d_in[7];  p.Whh = (const float*)d_in[8];
  p.bih = (const float*)d_in[9];  p.bhh = (const float*)d_in[10];
  p.W2  = (const float*)d_in[11]; p.b2  = (const float*)d_in[12];
  p.W3  = (const float*)d_in[13]; p.b3  = (const float*)d_in[14];
  p.wih8 = ws + WS_WIH8;
  p.w1e  = ws + WS_W1E;
  p.hbp  = (uint64_t*)(ws + WS_HBP);
  p.slt  = (uint64_t*)(ws + WS_SLT);
  p.out  = (float*)d_out;
  p.resident = resident;

  knet_main<<<NBLK, NTHR, (size_t)o.total, stream>>>(p);
}